// Round 12
// baseline (107.730 us; speedup 1.0000x reference)
//
#include <hip/hip_runtime.h>
#include <stdint.h>

typedef __bf16 bf16_t;
typedef __bf16 bf16x8 __attribute__((ext_vector_type(8)));
typedef float f32x4 __attribute__((ext_vector_type(4)));
typedef float f32x16 __attribute__((ext_vector_type(16)));
typedef unsigned short u16;
typedef unsigned short u16x4 __attribute__((ext_vector_type(4)));
typedef unsigned short u16x8 __attribute__((ext_vector_type(8)));
typedef unsigned int u32;
typedef unsigned int u32x4 __attribute__((ext_vector_type(4)));

#define DEVI __device__ __forceinline__

// ---- constants: B=2, S=2048, D=1024, H=16, DH=64 ----

DEVI u16 bits(float f) { bf16_t h = (bf16_t)f; return __builtin_bit_cast(u16, h); }

DEVI void gld16(const void* g, void* l) {
  __builtin_amdgcn_global_load_lds(
      (const __attribute__((address_space(1))) unsigned int*)g,
      (__attribute__((address_space(3))) unsigned int*)l, 16, 0, 0);
}

// swizzled 16B LDS read from a [rows][64] bf16 tile (128B rows), chunk cg (0..7)
DEVI bf16x8 ldsr(const u16* s, int row, int cg) {
  const int byte = row * 128 + ((cg ^ (row & 7)) << 4);
  return *(const bf16x8*)((const char*)s + byte);
}

// swizzled 16B LDS read from a [rows][128] bf16 tile (256B rows), chunk cg (0..15)
DEVI bf16x8 ldsrV(const u16* s, int row, int cg) {
  const int byte = row * 256 + ((cg ^ (row & 15)) << 4);
  return *(const bf16x8*)((const char*)s + byte);
}

DEVI float exp2v(float x) { return __builtin_amdgcn_exp2f(x); }

DEVI u32 cvtpk(float lo, float hi) {
  u32 r;
  asm("v_cvt_pk_bf16_f32 %0, %1, %2" : "=v"(r) : "v"(lo), "v"(hi));
  return r;
}

#define MFMA16(a, b, c) __builtin_amdgcn_mfma_f32_16x16x32_bf16(a, b, c, 0, 0, 0)
#define MFMA32(a, b, c) __builtin_amdgcn_mfma_f32_32x32x16_bf16(a, b, c, 0, 0, 0)

// Build PV A-frag (8 bf16, k-window of 16 kv) from 8 f32 P-regs (C-layout of
// 32x32 QK^T). swap(cvtpk(r0,r1),cvtpk(r4,r5)) -> words j01 & j45; similarly j23/j67.
#define MKFRAG(dst, S, B)                                              \
  {                                                                    \
    u32 a_ = cvtpk(S[(B) + 0], S[(B) + 1]);                            \
    u32 b_ = cvtpk(S[(B) + 4], S[(B) + 5]);                            \
    u32 c_ = cvtpk(S[(B) + 2], S[(B) + 3]);                            \
    u32 d_ = cvtpk(S[(B) + 6], S[(B) + 7]);                            \
    asm("v_permlane32_swap_b32 %0, %1" : "+v"(a_), "+v"(b_));          \
    asm("v_permlane32_swap_b32 %0, %1" : "+v"(c_), "+v"(d_));          \
    u32x4 u_ = {a_, c_, b_, d_};                                       \
    dst = __builtin_bit_cast(bf16x8, u_);                              \
  }

// ----- prep: x f32->bf16 (blocks 0..2047) + weight transpose (blocks 2048..3071)
__global__ void __launch_bounds__(256) prep(const float* __restrict__ x,
                                            const float* __restrict__ wqkv,
                                            const float* __restrict__ wout,
                                            u16* __restrict__ xb,
                                            u16* __restrict__ oqkv,
                                            u16* __restrict__ oout) {
  __shared__ float T[64][65];
  const int bid = blockIdx.x;
  const int tid = threadIdx.x;
  if (bid < 2048) {
    // cvt8: 8 f32 -> 8 bf16 per thread; 2048*256*8 = 4194304 elems exactly
    const int i = bid * 256 + tid;
    const f32x4* p = (const f32x4*)x;
    const f32x4 a = p[2 * i], b = p[2 * i + 1];
    u16x8 o;
#pragma unroll
    for (int j = 0; j < 4; ++j) { o[j] = bits(a[j]); o[4 + j] = bits(b[j]); }
    *(u16x8*)(xb + (size_t)i * 8) = o;
    return;
  }
  // tconv: in[K=1024][N] f32 -> out[N][1024] bf16, 64x64 tiles
  const int rem = bid - 2048;               // 1024 blocks
  const int bx = rem & 15, byy = rem >> 4;  // bx: k-tile (16), byy: n-tile (64)
  const int sel = byy >= 48;
  const float* in = sel ? wout : wqkv;
  u16* out = sel ? oout : oqkv;
  const int N = sel ? 1024 : 3072;
  const int k0 = bx * 64, n0 = (sel ? byy - 48 : byy) * 64;
#pragma unroll
  for (int i = 0; i < 4; ++i) {
    const int c = i * 256 + tid;          // 1024 chunks of float4
    const int row = c >> 4, c4 = c & 15;
    const f32x4 v = *(const f32x4*)(in + (size_t)(k0 + row) * N + n0 + c4 * 4);
#pragma unroll
    for (int j = 0; j < 4; ++j) T[row][c4 * 4 + j] = v[j];
  }
  __syncthreads();
#pragma unroll
  for (int i = 0; i < 2; ++i) {
    const int c = i * 256 + tid;          // 512 chunks of 8 bf16
    const int nrow = c >> 3, k8 = c & 7;
    u16x8 o;
#pragma unroll
    for (int j = 0; j < 8; ++j) o[j] = bits(T[k8 * 8 + j][nrow]);
    *(u16x8*)(out + (size_t)(n0 + nrow) * 1024 + k0 + k8 * 8) = o;
  }
}

// ====== 1-phase 256x192 QKV GEMM (dbuf, drain-0, 1 barrier/K-tile) ======
// 512 thr = 8 waves (2 Mrows x 4 Ncols); wave tile 128x48; BK=64; LDS 112 KiB.
// R11 FIX of R10's race: counted vmcnt(3) required a guaranteed ISSUE ORDER of
// the 7 staging gld16s; with A-stage and B-stage fused in one phase the
// compiler may interleave them, leaving an A-load in flight across the barrier
// -> iter t+1 ds_reads unlanded LDS (post-timing divergence). Fix: stage t+1
// (2-buffer) + vmcnt(0) drain — order-insensitive, no load crosses a barrier.
// Same shape as R9's gemm_out which passed repeated replays.

// stage one 128x64 half-tile from G[row0..row0+127][kt..kt+63] (stride 1024)
DEVI void stage_half(const u16* __restrict__ G, int row0, int kt, u16* dst) {
  const int tid = threadIdx.x;
  const int l = tid & 63, wv = tid >> 6;
  const u16* gp = G + (size_t)row0 * 1024 + kt;
#pragma unroll
  for (int i = 0; i < 2; ++i) {
    const int cb = i * 512 + wv * 64;   // wave-uniform chunk base
    const int c = cb + l;
    const int rih = c >> 3;
    const int col = ((c & 7) ^ (rih & 7)) << 3;   // inverse-swizzled source col
    gld16(gp + (size_t)rih * 1024 + col, dst + cb * 8);
  }
}

// stage one 64x64 quarter-tile (512 chunks, 1 gld16/thread)
DEVI void stage_q(const u16* __restrict__ G, int row0, int kt, u16* dst) {
  const int tid = threadIdx.x;
  const int l = tid & 63, wv = tid >> 6;
  const u16* gp = G + (size_t)row0 * 1024 + kt;
  const int cb = wv * 64;
  const int c = cb + l;
  const int rih = c >> 3;
  const int col = ((c & 7) ^ (rih & 7)) << 3;
  gld16(gp + (size_t)rih * 1024 + col, dst + cb * 8);
}

// One K-tile, single phase:
// {stage A(t+1)->An, B(t+1)->Bn} (any order), 22 ds_reads of tile t, lgkm(0),
// 48 MFMA, vmcnt(0) (drains ALL staging), ONE s_barrier.
// WAR: An/Bn last ds_read at iter t-1, sealed by t-1's lgkm(0)+barrier.
template <bool ST, bool VM>
DEVI void qkv_tile1(const u16* __restrict__ A, const u16* __restrict__ Bt,
                    int m0, int n0, int kt1,
                    u16* Ac, u16* Bc, u16* An, u16* Bn, f32x4 (&acc)[8][3]) {
  const int tid = threadIdx.x;
  const int l = tid & 63, wv = tid >> 6;
  const int lr = l & 15, lh = l >> 4;
  const int wr = wv >> 2, wc = wv & 3;
  const int ab = wr * 128, bb = wc * 48;
  // issue staging FIRST (latency hides under ds_read + MFMA below)
  if (ST) {
    stage_half(A, m0, kt1, An);
    stage_half(A, m0 + 128, kt1, An + 8192);
    stage_half(Bt, n0, kt1, Bn);
    stage_q(Bt, n0 + 128, kt1, Bn + 8192);
  }
  bf16x8 a[16], b0[4], b1[2];
#pragma unroll
  for (int m = 0; m < 8; ++m)
#pragma unroll
    for (int kk = 0; kk < 2; ++kk)
      a[m * 2 + kk] = ldsr(Ac, ab + m * 16 + lr, kk * 4 + lh);
#pragma unroll
  for (int n = 0; n < 2; ++n)
#pragma unroll
    for (int kk = 0; kk < 2; ++kk)
      b0[n * 2 + kk] = ldsr(Bc, bb + n * 16 + lr, kk * 4 + lh);
#pragma unroll
  for (int kk = 0; kk < 2; ++kk)
    b1[kk] = ldsr(Bc, bb + 32 + lr, kk * 4 + lh);
  asm volatile("s_waitcnt lgkmcnt(0)" ::: "memory");
  __builtin_amdgcn_sched_barrier(0);
  __builtin_amdgcn_s_setprio(1);
#pragma unroll
  for (int m = 0; m < 8; ++m)
#pragma unroll
    for (int n = 0; n < 2; ++n)
#pragma unroll
      for (int kk = 0; kk < 2; ++kk)
        acc[m][n] = MFMA16(a[m * 2 + kk], b0[n * 2 + kk], acc[m][n]);
#pragma unroll
  for (int m = 0; m < 8; ++m)
#pragma unroll
    for (int kk = 0; kk < 2; ++kk)
      acc[m][2] = MFMA16(a[m * 2 + kk], b1[kk], acc[m][2]);
  __builtin_amdgcn_s_setprio(0);
  if (VM) asm volatile("s_waitcnt vmcnt(0)" ::: "memory");
  __builtin_amdgcn_s_barrier();
}

// QKV GEMM: [4096][1024] x [3072][1024]^T -> Q(x0.125*log2e)/K row-major scatter,
// V written transposed into Vt[bh][dh][s] via packed u16x4 (8B) stores along s.
// 192-wide tiles may straddle the Q/K/V boundaries -> sel resolved per n-frag.
__global__ void __launch_bounds__(512, 2) gemm_qkv_k(const u16* __restrict__ A,
                                                     const u16* __restrict__ Bt,
                                                     u16* __restrict__ Qb,
                                                     u16* __restrict__ Kb,
                                                     u16* __restrict__ Vtb) {
  __shared__ u16 LA[2][16384], LB[2][12288];   // A 64K + B 48K = 112 KiB
  // 256 blocks = 16mt x 16nt; XCD g = bid&7 gets a contiguous 2(mt) x 16(nt) slab
  const int bid = blockIdx.x;
  const int g = bid & 7, w32 = bid >> 3;
  const int mt = g * 2 + (w32 >> 4);
  const int nt = w32 & 15;
  const int m0 = mt * 256, n0 = nt * 192;

  // prologue: T0 only; drain fully, barrier
  stage_half(A, m0, 0, LA[0]);
  stage_half(A, m0 + 128, 0, LA[0] + 8192);
  stage_half(Bt, n0, 0, LB[0]);
  stage_q(Bt, n0 + 128, 0, LB[0] + 8192);
  asm volatile("s_waitcnt vmcnt(0)" ::: "memory");
  __builtin_amdgcn_s_barrier();

  f32x4 acc[8][3] = {};
  u16 *Ac = LA[0], *Bc = LB[0], *An = LA[1], *Bn = LB[1];
#pragma unroll 1
  for (int t = 0; t < 15; ++t) {
    qkv_tile1<true, true>(A, Bt, m0, n0, (t + 1) * 64, Ac, Bc, An, Bn, acc);
    u16* tp = Ac; Ac = An; An = tp;
    tp = Bc; Bc = Bn; Bn = tp;
  }
  // t=15: pure compute (everything already resident and drained)
  qkv_tile1<false, false>(A, Bt, m0, n0, 0, Ac, Bc, An, Bn, acc);

  // epilogue: per-n-frag sel (16-aligned boundaries -> wave-uniform branch)
  const int tid = threadIdx.x;
  const int l = tid & 63, wv = tid >> 6;
  const int lr = l & 15, lh = l >> 4;
  const int wr = wv >> 2, wc = wv & 3;
  const int b = m0 >> 11, s0 = m0 & 2047;
#pragma unroll
  for (int n = 0; n < 3; ++n) {
    const int ng = n0 + wc * 48 + n * 16 + lr;
    const int sel = ng >> 10, h = (ng >> 6) & 15, dh = ng & 63;
    if (sel == 2) {
      // --- V: acc r-quad = 4 consecutive s -> one 8B store per m ---
      u16* vrow = Vtb + ((size_t)(b * 16 + h) * 64 + dh) * 2048 + s0;
#pragma unroll
      for (int m = 0; m < 8; ++m) {
        const int s = wr * 128 + m * 16 + lh * 4;
        u16x4 pk;
        pk[0] = bits(acc[m][n][0]);
        pk[1] = bits(acc[m][n][1]);
        pk[2] = bits(acc[m][n][2]);
        pk[3] = bits(acc[m][n][3]);
        *(u16x4*)(vrow + s) = pk;
      }
    } else {
      // --- Q/K: row-major scatter (proven path) ---
      u16* dst = sel == 0 ? Qb : Kb;
      // fold 1/sqrt(DH) AND log2(e) into Q so softmax uses exp2 directly
      const float qs = (sel == 0) ? 0.125f * 1.44269504f : 1.0f;
#pragma unroll
      for (int m = 0; m < 8; ++m) {
#pragma unroll
        for (int r = 0; r < 4; ++r) {
          const int mg = m0 + wr * 128 + m * 16 + lh * 4 + r;
          const int b2 = mg >> 11, s = mg & 2047;
          dst[((size_t)(b2 * 16 + h) * 2048 + s) * 64 + dh] = bits(acc[m][n][r] * qs);
        }
      }
    }
  }
}

// stage one 128x64 tile with 256 threads (4 gld16/thread), stride 1024
DEVI void stage_o(const u16* __restrict__ G, int row0, int kt, u16* dst) {
  const int tid = threadIdx.x;
  const int l = tid & 63, wv = tid >> 6;
  const u16* gp = G + (size_t)row0 * 1024 + kt;
#pragma unroll
  for (int i = 0; i < 4; ++i) {
    const int cb = i * 256 + wv * 64;   // wave-uniform chunk base
    const int c = cb + l;
    const int row = c >> 3;
    const int col = ((c & 7) ^ (row & 7)) << 3;
    gld16(gp + (size_t)row * 1024 + col, dst + cb * 8);
  }
}

// OUT GEMM: [4096][1024] x [1024][1024]^T + bias -> f32 out; 128x128 tiles.
// R9: T3 minimum-2-phase double-buffer — stage(t+1) issued BEFORE compute(t),
// one vmcnt(0)+barrier per K-tile (load latency hidden under ds_read+MFMA).
// grid dim3(8,32): XCD = linear%8 = n-tile -> each XCD reuses one 256KB B panel.
__global__ void __launch_bounds__(256) gemm_out_k(const u16* __restrict__ A,
                                                  const u16* __restrict__ Bt,
                                                  const float* __restrict__ bias,
                                                  float* __restrict__ out) {
  __shared__ u16 As[2][8192], Bs[2][8192];   // 2 bufs x (A 16KB + B 16KB) = 64KB
  const int m0 = blockIdx.y * 128, n0 = blockIdx.x * 128;
  const int tid = threadIdx.x;
  const int l = tid & 63, w = tid >> 6;
  const int lr = l & 15, lh = l >> 4;
  const int wr = w >> 1, wc = w & 1;

  f32x4 acc[4][4] = {};
  stage_o(A, m0, 0, As[0]);
  stage_o(Bt, n0, 0, Bs[0]);
  asm volatile("s_waitcnt vmcnt(0)" ::: "memory");
  __builtin_amdgcn_s_barrier();
  int cur = 0;
#pragma unroll 1
  for (int t = 0; t < 16; ++t) {
    // issue next-tile staging into the other buffer FIRST (latency hides
    // under this tile's ds_read+MFMA); drained by vmcnt(0) before barrier.
    if (t + 1 < 16) {
      stage_o(A, m0, (t + 1) * 64, As[cur ^ 1]);
      stage_o(Bt, n0, (t + 1) * 64, Bs[cur ^ 1]);
    }
    bf16x8 af[8], bfr[8];
#pragma unroll
    for (int m = 0; m < 4; ++m)
#pragma unroll
      for (int kk = 0; kk < 2; ++kk)
        af[m * 2 + kk] = ldsr(As[cur], wr * 64 + m * 16 + lr, kk * 4 + lh);
#pragma unroll
    for (int n = 0; n < 4; ++n)
#pragma unroll
      for (int kk = 0; kk < 2; ++kk)
        bfr[n * 2 + kk] = ldsr(Bs[cur], wc * 64 + n * 16 + lr, kk * 4 + lh);
    asm volatile("s_waitcnt lgkmcnt(0)" ::: "memory");
    __builtin_amdgcn_sched_barrier(0);
    __builtin_amdgcn_s_setprio(1);
#pragma unroll
    for (int m = 0; m < 4; ++m)
#pragma unroll
      for (int n = 0; n < 4; ++n)
#pragma unroll
        for (int kk = 0; kk < 2; ++kk)
          acc[m][n] = MFMA16(af[m * 2 + kk], bfr[n * 2 + kk], acc[m][n]);
    __builtin_amdgcn_s_setprio(0);
    if (t + 1 < 16) asm volatile("s_waitcnt vmcnt(0)" ::: "memory");
    __builtin_amdgcn_s_barrier();
    cur ^= 1;
  }

  // epilogue: bias add + f32 store (unchanged)
#pragma unroll
  for (int n = 0; n < 4; ++n) {
    const int ng = n0 + wc * 64 + n * 16 + lr;
    const float bv = bias[ng];
#pragma unroll
    for (int m = 0; m < 4; ++m) {
#pragma unroll
      for (int r = 0; r < 4; ++r) {
        const int mg = m0 + wr * 64 + m * 16 + lh * 4 + r;
        out[(size_t)mg * 1024 + ng] = acc[m][n][r] + bv;
      }
    }
  }
}

// ---- flash attention v8 (proven 44.8 us): T15 2-deep pipeline, ones-MFMA
// row-sum, kv-split 8 waves. Inner loop is schedule-fragile: R5's VALU row-sum
// variant regressed 10 us (MfmaUtil 39->25) -- do not re-order this loop.
// Occupancy is register-bound (48 acc + 64 VGPR = 112 -> 4 waves/SIMD hard cap).
__global__ void __launch_bounds__(512, 4) attn_k(const u16* __restrict__ Qb,
                                                 const u16* __restrict__ Kb,
                                                 const u16* __restrict__ Vt,
                                                 u16* __restrict__ Yb) {
  __shared__ char smem[65536];
  u16* const KsA = (u16*)smem;                // K tile buf0: [kv 128][dh 64]
  u16* const KsB = (u16*)(smem + 16384);      // K tile buf1
  u16* const VsA = (u16*)(smem + 32768);      // V^T tile buf0: [dh 64][kv 128]
  u16* const VsB = (u16*)(smem + 49152);      // V^T tile buf1

  const int tid = threadIdx.x;
  const int l = tid & 63, w = tid >> 6;
  const int lq = l & 31, hi = l >> 5;
  const int qw = w & 3;        // q-group within block (32 rows each)
  const int khalf = w >> 2;    // which 64-kv half of each staged tile
  // grid 512 = 32 bh x 16 qt; XCD swizzle (512 % 8 == 0, bijective)
  const int i0 = blockIdx.x;
  const int bid = (i0 & 7) * 64 + (i0 >> 3);
  const int bh = bid >> 4, qt = bid & 15;

  // Q B-frags: B[k=dh][col=q=lq]; lane reads Q[q=lq][dh = ks*16 + hi*8 ..+8]
  const u16* Qp = Qb + ((size_t)bh * 2048 + qt * 128 + qw * 32 + lq) * 64;
  bf16x8 qf0 = *(const bf16x8*)(Qp + hi * 8);
  bf16x8 qf1 = *(const bf16x8*)(Qp + 16 + hi * 8);
  bf16x8 qf2 = *(const bf16x8*)(Qp + 32 + hi * 8);
  bf16x8 qf3 = *(const bf16x8*)(Qp + 48 + hi * 8);

  const u16* Kbase = Kb + (size_t)bh * 2048 * 64;
  const u16* Vbase = Vt + (size_t)bh * 64 * 2048;

  bf16x8 ones;
#pragma unroll
  for (int j = 0; j < 8; ++j) ones[j] = (bf16_t)1.0f;

  f32x16 acc0 = {}, acc1 = {};  // O partial: row q=crow(r,hi), col dh=dhg*32+lq
  f32x16 accs = {};             // row-sum partial, same row layout (cols equal)

  // stage K [128][64] (1024 chunks) + V^T [64][128] (1024 chunks) over 512 thr
#define STAGE(Ksb, Vsb, kv0)                                               \
  {                                                                        \
    _Pragma("unroll") for (int ii = 0; ii < 2; ++ii) {                     \
      const int cb = ii * 512 + w * 64;                                    \
      const int c = cb + l;                                                \
      const int krow = c >> 3;                                             \
      const int kcol = ((c & 7) ^ (krow & 7)) << 3;                        \
      gld16(Kbase + (size_t)((kv0) + krow) * 64 + kcol, (Ksb) + cb * 8);   \
      const int vrow = c >> 4;                                             \
      const int vcol = ((c & 15) ^ (vrow & 15)) << 3;                      \
      gld16(Vbase + (size_t)vrow * 2048 + (kv0) + vcol, (Vsb) + cb * 8);   \
    }                                                                      \
  }

  STAGE(KsA, VsA, 0);
  asm volatile("s_waitcnt vmcnt(0)" ::: "memory");
  __builtin_amdgcn_s_barrier();

  bf16x8 pc0 = ones, pc1 = ones;  // carried frags: kv local 32-63 of prev tile
  int cur = 0;
#pragma unroll 1
  for (int t = 0; t < 16; ++t) {
    const u16* Ksc = cur ? KsB : KsA;   // tile t (K)
    const u16* Vsc = cur ? VsB : VsA;   // tile t (V)
    const u16* Vsp = cur ? VsA : VsB;   // tile t-1 (V) == staging target of t+1

    if (t > 0) {
      // ---- PV(t-1, sub1): must complete BEFORE stage(t+1) overwrites Vsp ----
      __builtin_amdgcn_s_setprio(1);
      accs = MFMA32(pc0, ones, accs);
      acc0 = MFMA32(pc0, ldsrV(Vsp, lq, khalf * 8 + 4 + hi), acc0);
      acc1 = MFMA32(pc0, ldsrV(Vsp, 32 + lq, khalf * 8 + 4 + hi), acc1);
      accs = MFMA32(pc1, ones, accs);
      acc0 = MFMA32(pc1, ldsrV(Vsp, lq, khalf * 8 + 6 + hi), acc0);
      acc1 = MFMA32(pc1, ldsrV(Vsp, 32 + lq, khalf * 8 + 6 + hi), acc1);
      __builtin_amdgcn_s_setprio(0);
      // stage(t) drain + rendezvous: tile t resident, all PV(t-1,1) reads done
      asm volatile("s_waitcnt vmcnt(0)" ::: "memory");
      __builtin_amdgcn_s_barrier();
    }
    if (t + 1 < 16) STAGE((cur ? KsA : KsB), (cur ? VsA : VsB), (t + 1) * 128);

    // ---- QK(t): s0 = kv 0-31, s1 = kv 32-63 of this wave's 64-half ----
    f32x16 s0 = {}, s1 = {};
    __builtin_amdgcn_s_setprio(1);
    s0 = MFMA32(ldsr(Ksc, khalf * 64 + lq, hi), qf0, s0);
    s0 = MFMA32(ldsr(Ksc, khalf * 64 + lq, 2 + hi), qf1, s0);
    s0 = MFMA32(ldsr(Ksc, khalf * 64 + lq, 4 + hi), qf2, s0);
    s0 = MFMA32(ldsr(Ksc, khalf * 64 + lq, 6 + hi), qf3, s0);
    // s1 chain interleaved with exp2(s0) (independent)
    s1 = MFMA32(ldsr(Ksc, khalf * 64 + 32 + lq, hi), qf0, s1);
    s0[0] = exp2v(s0[0]); s0[1] = exp2v(s0[1]); s0[2] = exp2v(s0[2]); s0[3] = exp2v(s0[3]);
    s1 = MFMA32(ldsr(Ksc, khalf * 64 + 32 + lq, 2 + hi), qf1, s1);
    s0[4] = exp2v(s0[4]); s0[5] = exp2v(s0[5]); s0[6] = exp2v(s0[6]); s0[7] = exp2v(s0[7]);
    s1 = MFMA32(ldsr(Ksc, khalf * 64 + 32 + lq, 4 + hi), qf2, s1);
    s0[8] = exp2v(s0[8]); s0[9] = exp2v(s0[9]); s0[10] = exp2v(s0[10]); s0[11] = exp2v(s0[11]);
    s1 = MFMA32(ldsr(Ksc, khalf * 64 + 32 + lq, 6 + hi), qf3, s1);
    s0[12] = exp2v(s0[12]); s0[13] = exp2v(s0[13]); s0[14] = exp2v(s0[14]); s0[15] = exp2v(s0[15]);
    __builtin_amdgcn_s_setprio(0);

    // frags for sub0 (kv 0-31)
    bf16x8 pa0, pa1;
    MKFRAG(pa0, s0, 0);
    MKFRAG(pa1, s0, 8);

    // ---- PV(t, sub0) MFMA interleaved with exp2(s1) VALU ----
    __builtin_amdgcn_s_setprio(1);
    accs = MFMA32(pa0, ones, accs);
    s1[0] = exp2v(s1[0]); s1[1] = exp2v(s1[1]); s1[2] = exp2v(s1[2]);
    acc0 = MFMA32(pa0, ldsrV(Vsc, lq, khalf * 8 + hi), acc0);
    s1[3] = exp2v(s1[3]); s1[4] = exp2v(s1[4]); s1[5] = exp2v(s1[5]);
    acc1 = MFMA32(pa0, ldsrV(Vsc, 32 + lq, khalf * 8 + hi), acc1);
    s1[6] = exp2v(s1[6]); s1[7] = exp2v(s1[7]); s1[8] = exp2v(s1[8]);
    accs = MFMA32(pa1, ones, accs);
    s1[9] = exp2v(s1[9]); s1[10] = exp2v(s1[10]); s1[11] = exp2v(s1[11]);
    acc0 = MFMA32(pa1, ldsrV(Vsc, lq, khalf * 8 + 2 + hi), acc0);
    s1[12] = exp2v(s1[12]); s1[13] = exp2v(s1[13]); s1[14] = exp2v(s1[14]);
    acc1 = MFMA32(pa1, ldsrV(Vsc, 32 + lq, khalf * 8 + 2 + hi), acc1);
    s1[15] = exp2v(s1[15]);
    __builtin_amdgcn_s_setprio(0);

    // frags for sub1 -> carried into next iteration
    MKFRAG(pc0, s1, 0);
    MKFRAG(pc1, s1, 8);
    cur ^= 1;
  }
  // ---- epilogue: PV(15, sub1); tile-15 V lives in buf[15&1] = (cur?VsA:VsB) ----
  {
    const u16* Vsp = cur ? VsA : VsB;
    accs = MFMA32(pc0, ones, accs);
    acc0 = MFMA32(pc0, ldsrV(Vsp, lq, khalf * 8 + 4 + hi), acc0);
    acc1 = MFMA32(pc0, ldsrV(Vsp, 32 + lq, khalf * 8 + 4 + hi), acc1);
    accs = MFMA32(pc1, ones, accs);
    acc0 = MFMA32(pc1, ldsrV(Vsp, lq, khalf * 8 + 6 + hi), acc0);
    acc1 = MFMA32(pc1, ldsrV(Vsp, 32 + lq, khalf * 8 + 6 + hi), acc1);
  }
#undef STAGE
  __syncthreads();  // all LDS reads done before smem reuse below

  // --- cross-wave combine: wave w+4 adds its kv-half partials into wave w ---
  // Per-lane slot stride 49 f32 (odd) -> conflict-free-ish; 256*49*4 = 50176 B.
  float* const F = (float*)smem;
  float* const Fp = F + (size_t)(tid & 255) * 49;
  if (khalf) {
#pragma unroll
    for (int r = 0; r < 16; ++r) {
      Fp[r] = acc0[r];
      Fp[16 + r] = acc1[r];
      Fp[32 + r] = accs[r];
    }
  }
  __syncthreads();
  if (khalf) return;
#pragma unroll
  for (int r = 0; r < 16; ++r) {
    acc0[r] += Fp[r];
    acc1[r] += Fp[16 + r];
    accs[r] += Fp[32 + r];
  }

  // epilogue: accs rows match acc rows exactly; divide and store
  const int b = bh >> 4, h = bh & 15;
#pragma unroll
  for (int r = 0; r < 16; ++r) {
    const float sd = 1.0f / accs[r];
    const int row = (r & 3) + 8 * (r >> 2) + 4 * hi;
    const int sq = qt * 128 + qw * 32 + row;
    u16* yp = Yb + ((size_t)b * 2048 + sq) * 1024 + h * 64;
    yp[lq] = bits(acc0[r] * sd);
    yp[32 + lq] = bits(acc1[r] * sd);
  }
}

extern "C" void kernel_launch(void* const* d_in, const int* in_sizes, int n_in,
                              void* d_out, int out_size, void* d_ws, size_t ws_size,
                              hipStream_t stream) {
  (void)in_sizes; (void)n_in; (void)out_size; (void)ws_size;
  const float* x     = (const float*)d_in[0];   // [2,2048,1024]
  const float* w_qkv = (const float*)d_in[1];   // [1024,3072]
  const float* w_out = (const float*)d_in[2];   // [1024,1024]
  const float* b_out = (const float*)d_in[3];   // [1024]
  float* out = (float*)d_out;

  // workspace layout (total 50,331,648 B)
  char* ws = (char*)d_ws;
  u16* xb    = (u16*)(ws);               // 8,388,608  x bf16 [4096][1024]
  u16* wqkvT = (u16*)(ws + 8388608);     // 6,291,456  w_qkv^T bf16 [3072][1024]
  u16* woutT = (u16*)(ws + 14680064);    // 2,097,152  w_out^T bf16 [1024][1024]
  u16* Qb    = (u16*)(ws + 16777216);    // 8,388,608  [BH][S][DH] (x0.125*log2e)
  u16* Kb    = (u16*)(ws + 25165824);    // 8,388,608  [BH][S][DH]
  u16* Vt    = (u16*)(ws + 41943040);    // 8,388,608  [BH][DH][S] (written by QKV GEMM)
  u16* Yb    = xb;                       // reuse xb after QKV GEMM

  prep<<<3072, 256, 0, stream>>>(x, w_qkv, w_out, xb, wqkvT, woutT);
  gemm_qkv_k<<<256, 512, 0, stream>>>(xb, wqkvT, Qb, Kb, Vt);
  attn_k<<<512, 512, 0, stream>>>(Qb, Kb, Vt, Yb);
  gemm_out_k<<<dim3(8, 32), 256, 0, stream>>>(Yb, woutT, b_out, out);
}

// Round 13
// 104.362 us; speedup vs baseline: 1.0323x; 1.0323x over previous
//
#include <hip/hip_runtime.h>
#include <stdint.h>

typedef __bf16 bf16_t;
typedef __bf16 bf16x8 __attribute__((ext_vector_type(8)));
typedef float f32x4 __attribute__((ext_vector_type(4)));
typedef float f32x16 __attribute__((ext_vector_type(16)));
typedef unsigned short u16;
typedef unsigned short u16x4 __attribute__((ext_vector_type(4)));
typedef unsigned short u16x8 __attribute__((ext_vector_type(8)));
typedef unsigned int u32;
typedef unsigned int u32x4 __attribute__((ext_vector_type(4)));

#define DEVI __device__ __forceinline__

// ---- constants: B=2, S=2048, D=1024, H=16, DH=64 ----

DEVI u16 bits(float f) { bf16_t h = (bf16_t)f; return __builtin_bit_cast(u16, h); }

DEVI void gld16(const void* g, void* l) {
  __builtin_amdgcn_global_load_lds(
      (const __attribute__((address_space(1))) unsigned int*)g,
      (__attribute__((address_space(3))) unsigned int*)l, 16, 0, 0);
}

// swizzled 16B LDS read from a [rows][64] bf16 tile (128B rows), chunk cg (0..7)
DEVI bf16x8 ldsr(const u16* s, int row, int cg) {
  const int byte = row * 128 + ((cg ^ (row & 7)) << 4);
  return *(const bf16x8*)((const char*)s + byte);
}

// swizzled 16B LDS read from a [rows][128] bf16 tile (256B rows), chunk cg (0..15)
DEVI bf16x8 ldsrV(const u16* s, int row, int cg) {
  const int byte = row * 256 + ((cg ^ (row & 15)) << 4);
  return *(const bf16x8*)((const char*)s + byte);
}

DEVI float exp2v(float x) { return __builtin_amdgcn_exp2f(x); }

DEVI u32 cvtpk(float lo, float hi) {
  u32 r;
  asm("v_cvt_pk_bf16_f32 %0, %1, %2" : "=v"(r) : "v"(lo), "v"(hi));
  return r;
}

#define MFMA16(a, b, c) __builtin_amdgcn_mfma_f32_16x16x32_bf16(a, b, c, 0, 0, 0)
#define MFMA32(a, b, c) __builtin_amdgcn_mfma_f32_32x32x16_bf16(a, b, c, 0, 0, 0)

// Build PV A-frag (8 bf16, k-window of 16 kv) from 8 f32 P-regs (C-layout of
// 32x32 QK^T). swap(cvtpk(r0,r1),cvtpk(r4,r5)) -> words j01 & j45; similarly j23/j67.
#define MKFRAG(dst, S, B)                                              \
  {                                                                    \
    u32 a_ = cvtpk(S[(B) + 0], S[(B) + 1]);                            \
    u32 b_ = cvtpk(S[(B) + 4], S[(B) + 5]);                            \
    u32 c_ = cvtpk(S[(B) + 2], S[(B) + 3]);                            \
    u32 d_ = cvtpk(S[(B) + 6], S[(B) + 7]);                            \
    asm("v_permlane32_swap_b32 %0, %1" : "+v"(a_), "+v"(b_));          \
    asm("v_permlane32_swap_b32 %0, %1" : "+v"(c_), "+v"(d_));          \
    u32x4 u_ = {a_, c_, b_, d_};                                       \
    dst = __builtin_bit_cast(bf16x8, u_);                              \
  }

// ----- prep: x f32->bf16 (blocks 0..2047) + weight transpose (blocks 2048..3071)
__global__ void __launch_bounds__(256) prep(const float* __restrict__ x,
                                            const float* __restrict__ wqkv,
                                            const float* __restrict__ wout,
                                            u16* __restrict__ xb,
                                            u16* __restrict__ oqkv,
                                            u16* __restrict__ oout) {
  __shared__ float T[64][65];
  const int bid = blockIdx.x;
  const int tid = threadIdx.x;
  if (bid < 2048) {
    // cvt8: 8 f32 -> 8 bf16 per thread; 2048*256*8 = 4194304 elems exactly
    const int i = bid * 256 + tid;
    const f32x4* p = (const f32x4*)x;
    const f32x4 a = p[2 * i], b = p[2 * i + 1];
    u16x8 o;
#pragma unroll
    for (int j = 0; j < 4; ++j) { o[j] = bits(a[j]); o[4 + j] = bits(b[j]); }
    *(u16x8*)(xb + (size_t)i * 8) = o;
    return;
  }
  // tconv: in[K=1024][N] f32 -> out[N][1024] bf16, 64x64 tiles
  const int rem = bid - 2048;               // 1024 blocks
  const int bx = rem & 15, byy = rem >> 4;  // bx: k-tile (16), byy: n-tile (64)
  const int sel = byy >= 48;
  const float* in = sel ? wout : wqkv;
  u16* out = sel ? oout : oqkv;
  const int N = sel ? 1024 : 3072;
  const int k0 = bx * 64, n0 = (sel ? byy - 48 : byy) * 64;
#pragma unroll
  for (int i = 0; i < 4; ++i) {
    const int c = i * 256 + tid;          // 1024 chunks of float4
    const int row = c >> 4, c4 = c & 15;
    const f32x4 v = *(const f32x4*)(in + (size_t)(k0 + row) * N + n0 + c4 * 4);
#pragma unroll
    for (int j = 0; j < 4; ++j) T[row][c4 * 4 + j] = v[j];
  }
  __syncthreads();
#pragma unroll
  for (int i = 0; i < 2; ++i) {
    const int c = i * 256 + tid;          // 512 chunks of 8 bf16
    const int nrow = c >> 3, k8 = c & 7;
    u16x8 o;
#pragma unroll
    for (int j = 0; j < 8; ++j) o[j] = bits(T[k8 * 8 + j][nrow]);
    *(u16x8*)(out + (size_t)(n0 + nrow) * 1024 + k0 + k8 * 8) = o;
  }
}

// ====== 2-phase 256x192 QKV GEMM (counted vmcnt, 256 blocks, 4 barriers/K) ======
// 512 thr = 8 waves (2 Mrows x 4 Ncols); wave tile 128x48; BK=64; LDS 112 KiB.
// Best-measured qkv variant (R8/R9, 104.5 us total). The counted vmcnt(3) is
// SOUND here (unlike R10's fused 1-phase) because the mid-tile barrier pins the
// issue order: A(t+1) stages in ph1, B(t+2) stages in ph2 -> queue at the ph2
// wait is exactly [B(t+1)x3, A(t+1)x4, B(t+2)x3] -> vmcnt(3) keeps only B(t+2)
// in flight across the barrier. Do NOT fuse the phases (R10 raced).

// stage one 128x64 half-tile from G[row0..row0+127][kt..kt+63] (stride 1024)
DEVI void stage_half(const u16* __restrict__ G, int row0, int kt, u16* dst) {
  const int tid = threadIdx.x;
  const int l = tid & 63, wv = tid >> 6;
  const u16* gp = G + (size_t)row0 * 1024 + kt;
#pragma unroll
  for (int i = 0; i < 2; ++i) {
    const int cb = i * 512 + wv * 64;   // wave-uniform chunk base
    const int c = cb + l;
    const int rih = c >> 3;
    const int col = ((c & 7) ^ (rih & 7)) << 3;   // inverse-swizzled source col
    gld16(gp + (size_t)rih * 1024 + col, dst + cb * 8);
  }
}

// stage one 64x64 quarter-tile (512 chunks, 1 gld16/thread)
DEVI void stage_q(const u16* __restrict__ G, int row0, int kt, u16* dst) {
  const int tid = threadIdx.x;
  const int l = tid & 63, wv = tid >> 6;
  const u16* gp = G + (size_t)row0 * 1024 + kt;
  const int cb = wv * 64;
  const int c = cb + l;
  const int rih = c >> 3;
  const int col = ((c & 7) ^ (rih & 7)) << 3;
  gld16(gp + (size_t)rih * 1024 + col, dst + cb * 8);
}

// One K-tile, 2 phases.
// Safety: all B(t) ds_reads are issued in ph1 and complete at ph1's lgkmcnt(0);
// ph1's end barrier orders that chip-wide, so ph2's B(t+2) stage into Bc is
// race-free. A(t+1) goes to the other buffer (An).
// vmcnt: queue at end-ph2 = [B(t+1)x3, A(t+1)x4, B(t+2)x3] -> vmcnt(3).
template <bool SA1, bool SB2, int VM>
DEVI void qkv_tile(const u16* __restrict__ A, const u16* __restrict__ Bt,
                   int m0, int n0, int ktA1, int ktB2,
                   u16* Ac, u16* Bc, u16* An, f32x4 (&acc)[8][3]) {
  const int tid = threadIdx.x;
  const int l = tid & 63, wv = tid >> 6;
  const int lr = l & 15, lh = l >> 4;
  const int wr = wv >> 2, wc = wv & 3;
  const int ab = wr * 128, bb = wc * 48;
  bf16x8 a[16], b0[4], b1[2];
  // ---- phase 1: 22 ds_reads + stage A(t+1) (both halves) + 32 MFMA ----
#pragma unroll
  for (int m = 0; m < 8; ++m)
#pragma unroll
    for (int kk = 0; kk < 2; ++kk)
      a[m * 2 + kk] = ldsr(Ac, ab + m * 16 + lr, kk * 4 + lh);
#pragma unroll
  for (int n = 0; n < 2; ++n)
#pragma unroll
    for (int kk = 0; kk < 2; ++kk)
      b0[n * 2 + kk] = ldsr(Bc, bb + n * 16 + lr, kk * 4 + lh);
#pragma unroll
  for (int kk = 0; kk < 2; ++kk)
    b1[kk] = ldsr(Bc, bb + 32 + lr, kk * 4 + lh);
  if (SA1) {
    stage_half(A, m0, ktA1, An);
    stage_half(A, m0 + 128, ktA1, An + 8192);
  }
  __builtin_amdgcn_s_barrier();
  asm volatile("s_waitcnt lgkmcnt(0)" ::: "memory");
  __builtin_amdgcn_sched_barrier(0);
  __builtin_amdgcn_s_setprio(1);
#pragma unroll
  for (int m = 0; m < 8; ++m)
#pragma unroll
    for (int n = 0; n < 2; ++n)
#pragma unroll
      for (int kk = 0; kk < 2; ++kk)
        acc[m][n] = MFMA16(a[m * 2 + kk], b0[n * 2 + kk], acc[m][n]);
  __builtin_amdgcn_s_setprio(0);
  __builtin_amdgcn_s_barrier();
  // ---- phase 2: stage B(t+2) (into Bc; safe, see above) + 16 MFMA + vmcnt ----
  if (SB2) {
    stage_half(Bt, n0, ktB2, Bc);
    stage_q(Bt, n0 + 128, ktB2, Bc + 8192);
  }
  __builtin_amdgcn_s_setprio(1);
#pragma unroll
  for (int m = 0; m < 8; ++m)
#pragma unroll
    for (int kk = 0; kk < 2; ++kk)
      acc[m][2] = MFMA16(a[m * 2 + kk], b1[kk], acc[m][2]);
  __builtin_amdgcn_s_setprio(0);
  if (VM == 3) asm volatile("s_waitcnt vmcnt(3)" ::: "memory");
  else if (VM == 0) asm volatile("s_waitcnt vmcnt(0)" ::: "memory");
  __builtin_amdgcn_s_barrier();
}

// QKV GEMM: [4096][1024] x [3072][1024]^T -> Q(x0.125*log2e)/K row-major scatter,
// V written transposed into Vt[bh][dh][s] via packed u16x4 (8B) stores along s.
// 192-wide tiles may straddle the Q/K/V boundaries -> sel resolved per n-frag.
__global__ void __launch_bounds__(512, 2) gemm_qkv_k(const u16* __restrict__ A,
                                                     const u16* __restrict__ Bt,
                                                     u16* __restrict__ Qb,
                                                     u16* __restrict__ Kb,
                                                     u16* __restrict__ Vtb) {
  __shared__ u16 LA[2][16384], LB[2][12288];   // A 64K + B 48K = 112 KiB
  // 256 blocks = 16mt x 16nt; XCD g = bid&7 gets a contiguous 2(mt) x 16(nt) slab
  const int bid = blockIdx.x;
  const int g = bid & 7, w32 = bid >> 3;
  const int mt = g * 2 + (w32 >> 4);
  const int nt = w32 & 15;
  const int m0 = mt * 256, n0 = nt * 192;

  // prologue: T0 fully + B(T1); 10 loads/thread; vmcnt(3) -> T0 resident
  stage_half(A, m0, 0, LA[0]);
  stage_half(A, m0 + 128, 0, LA[0] + 8192);
  stage_half(Bt, n0, 0, LB[0]);
  stage_q(Bt, n0 + 128, 0, LB[0] + 8192);
  stage_half(Bt, n0, 64, LB[1]);
  stage_q(Bt, n0 + 128, 64, LB[1] + 8192);
  asm volatile("s_waitcnt vmcnt(3)" ::: "memory");
  __builtin_amdgcn_s_barrier();

  f32x4 acc[8][3] = {};
  u16 *Ac = LA[0], *Bc = LB[0], *An = LA[1], *Bn = LB[1];
#pragma unroll 1
  for (int t = 0; t < 14; ++t) {
    qkv_tile<true, true, 3>(A, Bt, m0, n0, (t + 1) * 64, (t + 2) * 64, Ac, Bc, An, acc);
    u16* tp = Ac; Ac = An; An = tp;
    tp = Bc; Bc = Bn; Bn = tp;
  }
  // t=14: stage Ah(15), no Bh(16); drain to 0 so tile 15 is fully resident
  qkv_tile<true, false, 0>(A, Bt, m0, n0, 15 * 64, 0, Ac, Bc, An, acc);
  { u16* tp = Ac; Ac = An; An = tp; tp = Bc; Bc = Bn; Bn = tp; }
  // t=15: pure compute
  qkv_tile<false, false, -1>(A, Bt, m0, n0, 0, 0, Ac, Bc, An, acc);

  // epilogue: per-n-frag sel (16-aligned boundaries -> wave-uniform branch)
  const int tid = threadIdx.x;
  const int l = tid & 63, wv = tid >> 6;
  const int lr = l & 15, lh = l >> 4;
  const int wr = wv >> 2, wc = wv & 3;
  const int b = m0 >> 11, s0 = m0 & 2047;
#pragma unroll
  for (int n = 0; n < 3; ++n) {
    const int ng = n0 + wc * 48 + n * 16 + lr;
    const int sel = ng >> 10, h = (ng >> 6) & 15, dh = ng & 63;
    if (sel == 2) {
      // --- V: acc r-quad = 4 consecutive s -> one 8B store per m ---
      u16* vrow = Vtb + ((size_t)(b * 16 + h) * 64 + dh) * 2048 + s0;
#pragma unroll
      for (int m = 0; m < 8; ++m) {
        const int s = wr * 128 + m * 16 + lh * 4;
        u16x4 pk;
        pk[0] = bits(acc[m][n][0]);
        pk[1] = bits(acc[m][n][1]);
        pk[2] = bits(acc[m][n][2]);
        pk[3] = bits(acc[m][n][3]);
        *(u16x4*)(vrow + s) = pk;
      }
    } else {
      // --- Q/K: row-major scatter (proven path) ---
      u16* dst = sel == 0 ? Qb : Kb;
      // fold 1/sqrt(DH) AND log2(e) into Q so softmax uses exp2 directly
      const float qs = (sel == 0) ? 0.125f * 1.44269504f : 1.0f;
#pragma unroll
      for (int m = 0; m < 8; ++m) {
#pragma unroll
        for (int r = 0; r < 4; ++r) {
          const int mg = m0 + wr * 128 + m * 16 + lh * 4 + r;
          const int b2 = mg >> 11, s = mg & 2047;
          dst[((size_t)(b2 * 16 + h) * 2048 + s) * 64 + dh] = bits(acc[m][n][r] * qs);
        }
      }
    }
  }
}

// stage one 128x64 tile with 256 threads (4 gld16/thread), stride 1024
DEVI void stage_o(const u16* __restrict__ G, int row0, int kt, u16* dst) {
  const int tid = threadIdx.x;
  const int l = tid & 63, wv = tid >> 6;
  const u16* gp = G + (size_t)row0 * 1024 + kt;
#pragma unroll
  for (int i = 0; i < 4; ++i) {
    const int cb = i * 256 + wv * 64;   // wave-uniform chunk base
    const int c = cb + l;
    const int row = c >> 3;
    const int col = ((c & 7) ^ (row & 7)) << 3;
    gld16(gp + (size_t)row * 1024 + col, dst + cb * 8);
  }
}

// OUT GEMM: [4096][1024] x [1024][1024]^T + bias -> f32 out; 128x128 tiles.
// R9: T3 minimum-2-phase double-buffer — stage(t+1) issued BEFORE compute(t),
// one vmcnt(0)+barrier per K-tile (load latency hidden under ds_read+MFMA).
// grid dim3(8,32): XCD = linear%8 = n-tile -> each XCD reuses one 256KB B panel.
__global__ void __launch_bounds__(256) gemm_out_k(const u16* __restrict__ A,
                                                  const u16* __restrict__ Bt,
                                                  const float* __restrict__ bias,
                                                  float* __restrict__ out) {
  __shared__ u16 As[2][8192], Bs[2][8192];   // 2 bufs x (A 16KB + B 16KB) = 64KB
  const int m0 = blockIdx.y * 128, n0 = blockIdx.x * 128;
  const int tid = threadIdx.x;
  const int l = tid & 63, w = tid >> 6;
  const int lr = l & 15, lh = l >> 4;
  const int wr = w >> 1, wc = w & 1;

  f32x4 acc[4][4] = {};
  stage_o(A, m0, 0, As[0]);
  stage_o(Bt, n0, 0, Bs[0]);
  asm volatile("s_waitcnt vmcnt(0)" ::: "memory");
  __builtin_amdgcn_s_barrier();
  int cur = 0;
#pragma unroll 1
  for (int t = 0; t < 16; ++t) {
    // issue next-tile staging into the other buffer FIRST (latency hides
    // under this tile's ds_read+MFMA); drained by vmcnt(0) before barrier.
    if (t + 1 < 16) {
      stage_o(A, m0, (t + 1) * 64, As[cur ^ 1]);
      stage_o(Bt, n0, (t + 1) * 64, Bs[cur ^ 1]);
    }
    bf16x8 af[8], bfr[8];
#pragma unroll
    for (int m = 0; m < 4; ++m)
#pragma unroll
      for (int kk = 0; kk < 2; ++kk)
        af[m * 2 + kk] = ldsr(As[cur], wr * 64 + m * 16 + lr, kk * 4 + lh);
#pragma unroll
    for (int n = 0; n < 4; ++n)
#pragma unroll
      for (int kk = 0; kk < 2; ++kk)
        bfr[n * 2 + kk] = ldsr(Bs[cur], wc * 64 + n * 16 + lr, kk * 4 + lh);
    asm volatile("s_waitcnt lgkmcnt(0)" ::: "memory");
    __builtin_amdgcn_sched_barrier(0);
    __builtin_amdgcn_s_setprio(1);
#pragma unroll
    for (int m = 0; m < 4; ++m)
#pragma unroll
      for (int n = 0; n < 4; ++n)
#pragma unroll
        for (int kk = 0; kk < 2; ++kk)
          acc[m][n] = MFMA16(af[m * 2 + kk], bfr[n * 2 + kk], acc[m][n]);
    __builtin_amdgcn_s_setprio(0);
    if (t + 1 < 16) asm volatile("s_waitcnt vmcnt(0)" ::: "memory");
    __builtin_amdgcn_s_barrier();
    cur ^= 1;
  }

  // epilogue: bias add + f32 store (unchanged)
#pragma unroll
  for (int n = 0; n < 4; ++n) {
    const int ng = n0 + wc * 64 + n * 16 + lr;
    const float bv = bias[ng];
#pragma unroll
    for (int m = 0; m < 4; ++m) {
#pragma unroll
      for (int r = 0; r < 4; ++r) {
        const int mg = m0 + wr * 64 + m * 16 + lh * 4 + r;
        out[(size_t)mg * 1024 + ng] = acc[m][n][r] + bv;
      }
    }
  }
}

// ---- flash attention v8 (proven 44.8 us): T15 2-deep pipeline, ones-MFMA
// row-sum, kv-split 8 waves. Inner loop is schedule-fragile: R5's VALU row-sum
// variant regressed 10 us (MfmaUtil 39->25) -- do not re-order this loop.
// Occupancy is register-bound (48 acc + 64 VGPR = 112 -> 4 waves/SIMD hard cap).
__global__ void __launch_bounds__(512, 4) attn_k(const u16* __restrict__ Qb,
                                                 const u16* __restrict__ Kb,
                                                 const u16* __restrict__ Vt,
                                                 u16* __restrict__ Yb) {
  __shared__ char smem[65536];
  u16* const KsA = (u16*)smem;                // K tile buf0: [kv 128][dh 64]
  u16* const KsB = (u16*)(smem + 16384);      // K tile buf1
  u16* const VsA = (u16*)(smem + 32768);      // V^T tile buf0: [dh 64][kv 128]
  u16* const VsB = (u16*)(smem + 49152);      // V^T tile buf1

  const int tid = threadIdx.x;
  const int l = tid & 63, w = tid >> 6;
  const int lq = l & 31, hi = l >> 5;
  const int qw = w & 3;        // q-group within block (32 rows each)
  const int khalf = w >> 2;    // which 64-kv half of each staged tile
  // grid 512 = 32 bh x 16 qt; XCD swizzle (512 % 8 == 0, bijective)
  const int i0 = blockIdx.x;
  const int bid = (i0 & 7) * 64 + (i0 >> 3);
  const int bh = bid >> 4, qt = bid & 15;

  // Q B-frags: B[k=dh][col=q=lq]; lane reads Q[q=lq][dh = ks*16 + hi*8 ..+8]
  const u16* Qp = Qb + ((size_t)bh * 2048 + qt * 128 + qw * 32 + lq) * 64;
  bf16x8 qf0 = *(const bf16x8*)(Qp + hi * 8);
  bf16x8 qf1 = *(const bf16x8*)(Qp + 16 + hi * 8);
  bf16x8 qf2 = *(const bf16x8*)(Qp + 32 + hi * 8);
  bf16x8 qf3 = *(const bf16x8*)(Qp + 48 + hi * 8);

  const u16* Kbase = Kb + (size_t)bh * 2048 * 64;
  const u16* Vbase = Vt + (size_t)bh * 64 * 2048;

  bf16x8 ones;
#pragma unroll
  for (int j = 0; j < 8; ++j) ones[j] = (bf16_t)1.0f;

  f32x16 acc0 = {}, acc1 = {};  // O partial: row q=crow(r,hi), col dh=dhg*32+lq
  f32x16 accs = {};             // row-sum partial, same row layout (cols equal)

  // stage K [128][64] (1024 chunks) + V^T [64][128] (1024 chunks) over 512 thr
#define STAGE(Ksb, Vsb, kv0)                                               \
  {                                                                        \
    _Pragma("unroll") for (int ii = 0; ii < 2; ++ii) {                     \
      const int cb = ii * 512 + w * 64;                                    \
      const int c = cb + l;                                                \
      const int krow = c >> 3;                                             \
      const int kcol = ((c & 7) ^ (krow & 7)) << 3;                        \
      gld16(Kbase + (size_t)((kv0) + krow) * 64 + kcol, (Ksb) + cb * 8);   \
      const int vrow = c >> 4;                                             \
      const int vcol = ((c & 15) ^ (vrow & 15)) << 3;                      \
      gld16(Vbase + (size_t)vrow * 2048 + (kv0) + vcol, (Vsb) + cb * 8);   \
    }                                                                      \
  }

  STAGE(KsA, VsA, 0);
  asm volatile("s_waitcnt vmcnt(0)" ::: "memory");
  __builtin_amdgcn_s_barrier();

  bf16x8 pc0 = ones, pc1 = ones;  // carried frags: kv local 32-63 of prev tile
  int cur = 0;
#pragma unroll 1
  for (int t = 0; t < 16; ++t) {
    const u16* Ksc = cur ? KsB : KsA;   // tile t (K)
    const u16* Vsc = cur ? VsB : VsA;   // tile t (V)
    const u16* Vsp = cur ? VsA : VsB;   // tile t-1 (V) == staging target of t+1

    if (t > 0) {
      // ---- PV(t-1, sub1): must complete BEFORE stage(t+1) overwrites Vsp ----
      __builtin_amdgcn_s_setprio(1);
      accs = MFMA32(pc0, ones, accs);
      acc0 = MFMA32(pc0, ldsrV(Vsp, lq, khalf * 8 + 4 + hi), acc0);
      acc1 = MFMA32(pc0, ldsrV(Vsp, 32 + lq, khalf * 8 + 4 + hi), acc1);
      accs = MFMA32(pc1, ones, accs);
      acc0 = MFMA32(pc1, ldsrV(Vsp, lq, khalf * 8 + 6 + hi), acc0);
      acc1 = MFMA32(pc1, ldsrV(Vsp, 32 + lq, khalf * 8 + 6 + hi), acc1);
      __builtin_amdgcn_s_setprio(0);
      // stage(t) drain + rendezvous: tile t resident, all PV(t-1,1) reads done
      asm volatile("s_waitcnt vmcnt(0)" ::: "memory");
      __builtin_amdgcn_s_barrier();
    }
    if (t + 1 < 16) STAGE((cur ? KsA : KsB), (cur ? VsA : VsB), (t + 1) * 128);

    // ---- QK(t): s0 = kv 0-31, s1 = kv 32-63 of this wave's 64-half ----
    f32x16 s0 = {}, s1 = {};
    __builtin_amdgcn_s_setprio(1);
    s0 = MFMA32(ldsr(Ksc, khalf * 64 + lq, hi), qf0, s0);
    s0 = MFMA32(ldsr(Ksc, khalf * 64 + lq, 2 + hi), qf1, s0);
    s0 = MFMA32(ldsr(Ksc, khalf * 64 + lq, 4 + hi), qf2, s0);
    s0 = MFMA32(ldsr(Ksc, khalf * 64 + lq, 6 + hi), qf3, s0);
    // s1 chain interleaved with exp2(s0) (independent)
    s1 = MFMA32(ldsr(Ksc, khalf * 64 + 32 + lq, hi), qf0, s1);
    s0[0] = exp2v(s0[0]); s0[1] = exp2v(s0[1]); s0[2] = exp2v(s0[2]); s0[3] = exp2v(s0[3]);
    s1 = MFMA32(ldsr(Ksc, khalf * 64 + 32 + lq, 2 + hi), qf1, s1);
    s0[4] = exp2v(s0[4]); s0[5] = exp2v(s0[5]); s0[6] = exp2v(s0[6]); s0[7] = exp2v(s0[7]);
    s1 = MFMA32(ldsr(Ksc, khalf * 64 + 32 + lq, 4 + hi), qf2, s1);
    s0[8] = exp2v(s0[8]); s0[9] = exp2v(s0[9]); s0[10] = exp2v(s0[10]); s0[11] = exp2v(s0[11]);
    s1 = MFMA32(ldsr(Ksc, khalf * 64 + 32 + lq, 6 + hi), qf3, s1);
    s0[12] = exp2v(s0[12]); s0[13] = exp2v(s0[13]); s0[14] = exp2v(s0[14]); s0[15] = exp2v(s0[15]);
    __builtin_amdgcn_s_setprio(0);

    // frags for sub0 (kv 0-31)
    bf16x8 pa0, pa1;
    MKFRAG(pa0, s0, 0);
    MKFRAG(pa1, s0, 8);

    // ---- PV(t, sub0) MFMA interleaved with exp2(s1) VALU ----
    __builtin_amdgcn_s_setprio(1);
    accs = MFMA32(pa0, ones, accs);
    s1[0] = exp2v(s1[0]); s1[1] = exp2v(s1[1]); s1[2] = exp2v(s1[2]);
    acc0 = MFMA32(pa0, ldsrV(Vsc, lq, khalf * 8 + hi), acc0);
    s1[3] = exp2v(s1[3]); s1[4] = exp2v(s1[4]); s1[5] = exp2v(s1[5]);
    acc1 = MFMA32(pa0, ldsrV(Vsc, 32 + lq, khalf * 8 + hi), acc1);
    s1[6] = exp2v(s1[6]); s1[7] = exp2v(s1[7]); s1[8] = exp2v(s1[8]);
    accs = MFMA32(pa1, ones, accs);
    s1[9] = exp2v(s1[9]); s1[10] = exp2v(s1[10]); s1[11] = exp2v(s1[11]);
    acc0 = MFMA32(pa1, ldsrV(Vsc, lq, khalf * 8 + 2 + hi), acc0);
    s1[12] = exp2v(s1[12]); s1[13] = exp2v(s1[13]); s1[14] = exp2v(s1[14]);
    acc1 = MFMA32(pa1, ldsrV(Vsc, 32 + lq, khalf * 8 + 2 + hi), acc1);
    s1[15] = exp2v(s1[15]);
    __builtin_amdgcn_s_setprio(0);

    // frags for sub1 -> carried into next iteration
    MKFRAG(pc0, s1, 0);
    MKFRAG(pc1, s1, 8);
    cur ^= 1;
  }
  // ---- epilogue: PV(15, sub1); tile-15 V lives in buf[15&1] = (cur?VsA:VsB) ----
  {
    const u16* Vsp = cur ? VsA : VsB;
    accs = MFMA32(pc0, ones, accs);
    acc0 = MFMA32(pc0, ldsrV(Vsp, lq, khalf * 8 + 4 + hi), acc0);
    acc1 = MFMA32(pc0, ldsrV(Vsp, 32 + lq, khalf * 8 + 4 + hi), acc1);
    accs = MFMA32(pc1, ones, accs);
    acc0 = MFMA32(pc1, ldsrV(Vsp, lq, khalf * 8 + 6 + hi), acc0);
    acc1 = MFMA32(pc1, ldsrV(Vsp, 32 + lq, khalf * 8 + 6 + hi), acc1);
  }
#undef STAGE
  __syncthreads();  // all LDS reads done before smem reuse below

  // --- cross-wave combine: wave w+4 adds its kv-half partials into wave w ---
  // Per-lane slot stride 49 f32 (odd) -> conflict-free-ish; 256*49*4 = 50176 B.
  float* const F = (float*)smem;
  float* const Fp = F + (size_t)(tid & 255) * 49;
  if (khalf) {
#pragma unroll
    for (int r = 0; r < 16; ++r) {
      Fp[r] = acc0[r];
      Fp[16 + r] = acc1[r];
      Fp[32 + r] = accs[r];
    }
  }
  __syncthreads();
  if (khalf) return;
#pragma unroll
  for (int r = 0; r < 16; ++r) {
    acc0[r] += Fp[r];
    acc1[r] += Fp[16 + r];
    accs[r] += Fp[32 + r];
  }

  // epilogue: accs rows match acc rows exactly; divide and store
  const int b = bh >> 4, h = bh & 15;
#pragma unroll
  for (int r = 0; r < 16; ++r) {
    const float sd = 1.0f / accs[r];
    const int row = (r & 3) + 8 * (r >> 2) + 4 * hi;
    const int sq = qt * 128 + qw * 32 + row;
    u16* yp = Yb + ((size_t)b * 2048 + sq) * 1024 + h * 64;
    yp[lq] = bits(acc0[r] * sd);
    yp[32 + lq] = bits(acc1[r] * sd);
  }
}

extern "C" void kernel_launch(void* const* d_in, const int* in_sizes, int n_in,
                              void* d_out, int out_size, void* d_ws, size_t ws_size,
                              hipStream_t stream) {
  (void)in_sizes; (void)n_in; (void)out_size; (void)ws_size;
  const float* x     = (const float*)d_in[0];   // [2,2048,1024]
  const float* w_qkv = (const float*)d_in[1];   // [1024,3072]
  const float* w_out = (const float*)d_in[2];   // [1024,1024]
  const float* b_out = (const float*)d_in[3];   // [1024]
  float* out = (float*)d_out;

  // workspace layout (total 50,331,648 B)
  char* ws = (char*)d_ws;
  u16* xb    = (u16*)(ws);               // 8,388,608  x bf16 [4096][1024]
  u16* wqkvT = (u16*)(ws + 8388608);     // 6,291,456  w_qkv^T bf16 [3072][1024]
  u16* woutT = (u16*)(ws + 14680064);    // 2,097,152  w_out^T bf16 [1024][1024]
  u16* Qb    = (u16*)(ws + 16777216);    // 8,388,608  [BH][S][DH] (x0.125*log2e)
  u16* Kb    = (u16*)(ws + 25165824);    // 8,388,608  [BH][S][DH]
  u16* Vt    = (u16*)(ws + 41943040);    // 8,388,608  [BH][DH][S] (written by QKV GEMM)
  u16* Yb    = xb;                       // reuse xb after QKV GEMM

  prep<<<3072, 256, 0, stream>>>(x, w_qkv, w_out, xb, wqkvT, woutT);
  gemm_qkv_k<<<256, 512, 0, stream>>>(xb, wqkvT, Qb, Kb, Vt);
  attn_k<<<512, 512, 0, stream>>>(Qb, Kb, Vt, Yb);
  gemm_out_k<<<dim3(8, 32), 256, 0, stream>>>(Yb, woutT, b_out, out);
}